// Round 1
// 6240.248 us; speedup vs baseline: 1.0065x; 1.0065x over previous
//
#include <hip/hip_runtime.h>

// LSTM T=16384, B=32, H=96. 32 blocks x 384 thr. R13 = 6722us -> R14 = 6280us
// (XOR-indexed weights). R15 (this): chain-fold bundle -- every op removed from
// the serial recurrence chain is worth ~8 cy (R12->R13 evidence):
//   1. e_k folded into W/w_ih/bias at register-load (per XOR slot d the gate is
//      s^d, so scale each slot's rows by e_k(s^d)) -> kills the pre*e_k mul.
//   2. gx = fma(xv,wih',bias') folded into acc[0] init (slot 0 = own gate,
//      never crosses lanes in the butterfly) -> kills the post-butterfly add;
//      gx computed off-chain per 4-step block.
//   3. c kept in scaled domain c' = -2*log2e*c: g-gate act constants become
//      (-4k,+2k) (free), c-update unchanged in form, tanh(c) = 2*rcp(1+2^c')-1
//      -> kills the tanh-input mul.
//   4. h = fma(ov+ov, r, -ov) (o2 off-chain, neg is a free VOP3 modifier)
//      -> one fewer chain op in the tail.
// Everything else identical: slot-shifted 513-row h history, float4 x
// broadcast per 4 steps, v_dot2_f32_f16 dots (48 weight VGPRs), XOR quad
// butterfly, one barrier/step, bulk fc flush every 512 steps.

constexpr int HH   = 96;
constexpr int BB   = 32;
constexpr int TT   = 16384;
constexpr int TH   = 384;   // 6 waves
constexpr int NS   = 512;   // h history window
constexpr int ROWP = 104;   // halves per hist row: 208 B, 16B-aligned

typedef _Float16 f16x2 __attribute__((ext_vector_type(2)));

__device__ __forceinline__ float dot2_f16(f16x2 a, f16x2 b, float c) {
    float d;
    int ai = __builtin_bit_cast(int, a);
    int bi = __builtin_bit_cast(int, b);
    asm("v_dot2_f32_f16 %0, %1, %2, %3" : "=v"(d) : "v"(ai), "v"(bi), "v"(c));
    return d;
}

// a + (b cross-laned by CTRL)   [fused to v_add_f32_dpp by GCNDPPCombine]
template <int CTRL>
__device__ __forceinline__ float dpp_add2(float a, float b) {
    int r = __builtin_amdgcn_mov_dpp(__builtin_bit_cast(int, b), CTRL, 0xF, 0xF, true);
    return a + __builtin_bit_cast(float, r);
}
template <int CTRL>
__device__ __forceinline__ float dpp_bcast(float v) {
    int r = __builtin_amdgcn_mov_dpp(__builtin_bit_cast(int, v), CTRL, 0xF, 0xF, true);
    return __builtin_bit_cast(float, r);
}
constexpr int DPP_XOR1 = 0xB1;  // quad_perm [1,0,3,2]
constexpr int DPP_XOR2 = 0x4E;  // quad_perm [2,3,0,1]
constexpr int DPP_B1   = 0x55;
constexpr int DPP_B2   = 0xAA;
constexpr int DPP_B3   = 0xFF;

#define LOG2E 1.44269504f

__attribute__((amdgpu_flat_work_group_size(TH, TH), amdgpu_waves_per_eu(1, 2)))
__global__ void lstm_kernel(const float* __restrict__ x,
                            const float* __restrict__ w_ih,
                            const float* __restrict__ w_hh,
                            const float* __restrict__ b_ih,
                            const float* __restrict__ b_hh,
                            const float* __restrict__ fc_w,
                            const float* __restrict__ fc_b,
                            float* __restrict__ out) {
    __shared__ __align__(16) _Float16 hist[(NS + 1) * ROWP];  // ~104 KB
    __shared__ __align__(16) float xs[NS];                    // 2 KB x window
    __shared__ float fcw_s[HH];

    const int tid = threadIdx.x;
    const int b   = blockIdx.x;
    const int j   = tid >> 2;    // cell 0..95
    const int s   = tid & 3;     // k-slice [24s,24s+24) halves; also "my gate"

    // XOR-indexed weight layout: slot d holds gate (s^d)'s row slice,
    // PRE-SCALED by e_k(gate) so exp2 consumes the dot output directly.
    f16x2 W[4][12];
#pragma unroll
    for (int d = 0; d < 4; ++d) {
        const int gate = s ^ d;
        const float ek = (gate == 2) ? (-2.0f * LOG2E) : (-LOG2E);
        const float* wr = w_hh + ((gate * HH) + j) * HH + 24 * s;
#pragma unroll
        for (int m = 0; m < 12; ++m)
            W[d][m] = f16x2{(_Float16)(wr[2 * m] * ek), (_Float16)(wr[2 * m + 1] * ek)};
    }
#pragma unroll
    for (int d = 0; d < 4; ++d)
#pragma unroll
        for (int m = 0; m < 12; ++m) asm volatile("" : "+v"(W[d][m]));

    const float ek_s  = (s == 2) ? (-2.0f * LOG2E) : (-LOG2E);
    const float wih2  = w_ih[s * HH + j] * ek_s;
    const float bias2 = (b_ih[s * HH + j] + b_hh[s * HH + j]) * ek_s;
    // act = fma(rcp(1+2^pre'), a_mul, a_add):
    //   sigmoid gates: (1, 0);  g gate: g' = -2k*tanh = -4k*rcp + 2k
    const float a_mul = (s == 2) ? (-4.0f * LOG2E) : 1.0f;
    const float a_add = (s == 2) ? (2.0f * LOG2E) : 0.0f;

    const float fcb = fc_b[0];
    float c = 0.0f;   // scaled domain: c' = -2*log2e * c_true

    for (int i = tid; i < HH; i += TH) fcw_s[i] = fc_w[i];

    // Bulk fc projection for window [t0, t0+NS): h(t0+i) is in hist row i+1.
    auto flush = [&](int t0) {
        for (int i = tid; i < NS; i += TH) {
            const uint2* hr = (const uint2*)(hist + (i + 1) * ROWP);
            float a = 0.0f;
#pragma unroll
            for (int m = 0; m < 24; ++m) {
                uint2 u = hr[m];
                f16x2 p0 = __builtin_bit_cast(f16x2, u.x);
                f16x2 p1 = __builtin_bit_cast(f16x2, u.y);
                a = fmaf((float)p0.x, fcw_s[4 * m + 0], a);
                a = fmaf((float)p0.y, fcw_s[4 * m + 1], a);
                a = fmaf((float)p1.x, fcw_s[4 * m + 2], a);
                a = fmaf((float)p1.y, fcw_s[4 * m + 3], a);
            }
            out[(t0 + i) * BB + b] = a + fcb + xs[i];
        }
    };

    const _Float16* rd_p;  // h(t-1) slice base; advanced 4 rows at a time
    _Float16*       wr_p;  // h(t) cell slot base

    auto step = [&](float gx, const int ofs) {   // ofs: constant element offset
        const uint4* hrow = (const uint4*)(rd_p + ofs);
        uint4 u0 = hrow[0], u1 = hrow[1], u2 = hrow[2];
        f16x2 h2[12] = {
            __builtin_bit_cast(f16x2, u0.x), __builtin_bit_cast(f16x2, u0.y),
            __builtin_bit_cast(f16x2, u0.z), __builtin_bit_cast(f16x2, u0.w),
            __builtin_bit_cast(f16x2, u1.x), __builtin_bit_cast(f16x2, u1.y),
            __builtin_bit_cast(f16x2, u1.z), __builtin_bit_cast(f16x2, u1.w),
            __builtin_bit_cast(f16x2, u2.x), __builtin_bit_cast(f16x2, u2.y),
            __builtin_bit_cast(f16x2, u2.z), __builtin_bit_cast(f16x2, u2.w)};

        float acc[4];
        acc[0] = gx;       // own gate's x+bias term rides slot 0 (lane-local)
        acc[1] = 0.0f;
        acc[2] = 0.0f;
        acc[3] = 0.0f;
#pragma unroll
        for (int d = 0; d < 4; ++d) {
            float e = acc[d];
#pragma unroll
            for (int m = 0; m < 12; ++m) e = dot2_f16(W[d][m], h2[m], e);
            acc[d] = e;
        }
        // XOR butterfly: lane s ends with gate s's full pre-scaled sum.
        const float b0  = dpp_add2<DPP_XOR1>(acc[0], acc[1]);
        const float b1  = dpp_add2<DPP_XOR1>(acc[2], acc[3]);
        const float pre = dpp_add2<DPP_XOR2>(b0, b1);

        const float act =
            fmaf(__builtin_amdgcn_rcpf(1.0f + __builtin_amdgcn_exp2f(pre)),
                 a_mul, a_add);
        const float fv = dpp_bcast<DPP_B1>(act);
        const float gv = dpp_bcast<DPP_B2>(act);   // already -2k-scaled
        const float ov = dpp_bcast<DPP_B3>(act);
        c = fmaf(fv, c, act * gv);                 // stays in scaled domain
        // tanh(c_true) = 2*rcp(1+2^c') - 1 ; h = o*tanh = fma(2o, r, -o)
        const float r  = __builtin_amdgcn_rcpf(1.0f + __builtin_amdgcn_exp2f(c));
        const float o2 = ov + ov;                  // off-chain
        const float h  = fmaf(o2, r, -ov);
        if (s == 0) *(wr_p + ofs) = (_Float16)h;
        __syncthreads();
    };

    for (int w = 0; w < TT / NS; ++w) {
        const int t0 = w * NS;
        if (w == 0) {
            if (tid < 48) ((uint32_t*)hist)[tid] = 0u;  // row 0 = h(-1) = 0
        } else {
            flush(t0 - NS);                              // old xs + rows 1..512
            if (tid < 48)                                // row 512 -> row 0
                ((uint32_t*)hist)[tid] = ((const uint32_t*)(hist + NS * ROWP))[tid];
        }
        __syncthreads();
        for (int i = tid; i < NS; i += TH) xs[i] = x[(t0 + i) * BB + b];
        __syncthreads();

        rd_p = hist + 24 * s;
        wr_p = hist + ROWP + j;
        for (int tt = 0; tt < NS; tt += 4) {
            const float4 xq = *(const float4*)(xs + tt);  // broadcast
            const float gx0 = fmaf(xq.x, wih2, bias2);    // off-chain
            const float gx1 = fmaf(xq.y, wih2, bias2);
            const float gx2 = fmaf(xq.z, wih2, bias2);
            const float gx3 = fmaf(xq.w, wih2, bias2);
            step(gx0, 0 * ROWP);
            step(gx1, 1 * ROWP);
            step(gx2, 2 * ROWP);
            step(gx3, 3 * ROWP);
            rd_p += 4 * ROWP;
            wr_p += 4 * ROWP;
        }
    }
    flush(TT - NS);   // last window (loop ended with a barrier)
}

extern "C" void kernel_launch(void* const* d_in, const int* in_sizes, int n_in,
                              void* d_out, int out_size, void* d_ws, size_t ws_size,
                              hipStream_t stream) {
    const float* x    = (const float*)d_in[0];
    const float* w_ih = (const float*)d_in[1];
    const float* w_hh = (const float*)d_in[2];
    const float* b_ih = (const float*)d_in[3];
    const float* b_hh = (const float*)d_in[4];
    const float* fc_w = (const float*)d_in[5];
    const float* fc_b = (const float*)d_in[6];
    float* out = (float*)d_out;

    lstm_kernel<<<dim3(BB), dim3(TH), 0, stream>>>(x, w_ih, w_hh, b_ih, b_hh,
                                                   fc_w, fc_b, out);
}